// Round 6
// baseline (135.788 us; speedup 1.0000x reference)
//
#include <hip/hip_runtime.h>
#include <hip/hip_bf16.h>
#include <stdint.h>

// Problem: B=16, S=1024, IN=1024, OUT=1024.
// Reference collapses: softmax row-sums are exactly 1 (key mask always has >=1
// live column), so out = leaky_relu(xs @ (Wlin@Wv)^T + (Wlin@bv + blin)).
//
// Round 6: fix round-5's pipeline serialization. A-loads issued 2 tiles ahead
// (double reg buffer), B gload_lds 1 tile ahead, single counted vmcnt(12) per
// K-tile (never 0 in steady state, T4). cvt+ds_write after MFMA in P1/P2.

#define M_TOT 16384   // B*S
#define KDIM  1024
#define NDIM  1024
#define NKT   16      // K-tiles of BK=64 in main GEMM

typedef __attribute__((ext_vector_type(8))) short bf16x8;
typedef __attribute__((ext_vector_type(4))) float f32x4;
typedef __attribute__((ext_vector_type(4))) unsigned short u16x4;
typedef __attribute__((ext_vector_type(8))) unsigned short u16x8;

static __device__ __forceinline__ unsigned short f2bf(float f) {
    union { float f; unsigned int u; } v; v.f = f;
    unsigned int u = v.u;
    return (unsigned short)((u + 0x7fffu + ((u >> 16) & 1u)) >> 16);  // RNE
}

static __device__ __forceinline__ u16x8 pack8(float4 a, float4 b) {
    u16x8 p = { f2bf(a.x), f2bf(a.y), f2bf(a.z), f2bf(a.w),
                f2bf(b.x), f2bf(b.y), f2bf(b.z), f2bf(b.w) };
    return p;
}

static __device__ __forceinline__ void gload16(const void* g, void* l) {
    __builtin_amdgcn_global_load_lds(
        (__attribute__((address_space(1))) void*)(g),
        (__attribute__((address_space(3))) void*)(l), 16, 0, 0);
}

// Involutive byte-swizzle for [rows][64]bf16 (128B-stride) LDS tiles: XOR row
// bits (7-9) into 16B-slot bits (4-6). 16-way column conflict -> free 2-way.
static __device__ __forceinline__ int swz128(int p) {
    return p ^ (((p >> 7) & 7) << 4);
}

// ---------------------------------------------------------------------------
// prep0: [0,256) transpose Wv[d][i] -> Wvt[i][d] bf16 (64x64 tiles, padded
//        fp32 LDS); [256,512) Wlin -> Wlb bf16; [512,768) bias fold.
// ---------------------------------------------------------------------------
__global__ __launch_bounds__(256) void prep0_kernel(
    const float* __restrict__ Wv, const float* __restrict__ Wlin,
    const float* __restrict__ bv, const float* __restrict__ blin,
    unsigned short* __restrict__ Wvt, unsigned short* __restrict__ Wlb,
    float* __restrict__ bcomb) {
    __shared__ float Tl[64 * 65];
    const int bid = blockIdx.x;
    const int t = threadIdx.x;

    if (bid < 256) {
        const int dt = bid >> 4;
        const int it = bid & 15;
        const int r = t >> 2;
        const int c0 = (t & 3) * 16;
        #pragma unroll
        for (int u = 0; u < 4; ++u) {
            float4 v = *(const float4*)&Wv[((size_t)(dt * 64 + r)) * NDIM + it * 64 + c0 + 4 * u];
            Tl[r * 65 + c0 + 4 * u + 0] = v.x;
            Tl[r * 65 + c0 + 4 * u + 1] = v.y;
            Tl[r * 65 + c0 + 4 * u + 2] = v.z;
            Tl[r * 65 + c0 + 4 * u + 3] = v.w;
        }
        __syncthreads();
        const int i = t >> 2;
        const int dq = (t & 3) * 16;
        float v[16];
        #pragma unroll
        for (int u = 0; u < 16; ++u) v[u] = Tl[(dq + u) * 65 + i];
        u16x8 p0 = { f2bf(v[0]), f2bf(v[1]), f2bf(v[2]), f2bf(v[3]),
                     f2bf(v[4]), f2bf(v[5]), f2bf(v[6]), f2bf(v[7]) };
        u16x8 p1 = { f2bf(v[8]), f2bf(v[9]), f2bf(v[10]), f2bf(v[11]),
                     f2bf(v[12]), f2bf(v[13]), f2bf(v[14]), f2bf(v[15]) };
        unsigned short* dst = &Wvt[((size_t)(it * 64 + i)) * KDIM + dt * 64 + dq];
        *(u16x8*)dst = p0;
        *(u16x8*)(dst + 8) = p1;
    } else if (bid < 512) {
        const size_t idx = (((size_t)(bid - 256)) * 256 + t) * 16;
        float4 a = *(const float4*)&Wlin[idx];
        float4 b = *(const float4*)&Wlin[idx + 4];
        float4 c = *(const float4*)&Wlin[idx + 8];
        float4 d = *(const float4*)&Wlin[idx + 12];
        *(u16x8*)&Wlb[idx] = pack8(a, b);
        *(u16x8*)&Wlb[idx + 8] = pack8(c, d);
    } else {
        const int wave = t >> 6, lane = t & 63;
        const int o = (bid - 512) * 4 + wave;
        float s = 0.f;
        for (int d = lane; d < KDIM; d += 64) s += Wlin[o * KDIM + d] * bv[d];
        #pragma unroll
        for (int off = 32; off > 0; off >>= 1) s += __shfl_down(s, off, 64);
        if (lane == 0) bcomb[o] = s + blin[o];
    }
}

// ---------------------------------------------------------------------------
// wcomb: Wc[o][i] = sum_d Wlb[o][d] * Wvt[i][d]. 64x64 tiles, 256 blocks,
// 4 waves (2x2 of 32x32), both operands via global_load_lds.
// ---------------------------------------------------------------------------
__global__ __launch_bounds__(256) void wcomb_kernel(
    const unsigned short* __restrict__ Wlb, const unsigned short* __restrict__ Wvt,
    unsigned short* __restrict__ Wc) {
    __shared__ unsigned short As[64 * 32];
    __shared__ unsigned short Bs[64 * 32];
    const int t = threadIdx.x;
    const int ot = blockIdx.x >> 4;
    const int it = blockIdx.x & 15;
    const int w = t >> 6, l = t & 63;
    const int wr = (w >> 1) * 32, wc = (w & 1) * 32;
    const int lr = l & 15, lk = l >> 4;

    f32x4 acc[2][2] = {};

    const unsigned short* gA = &Wlb[((size_t)(ot * 64 + (t >> 2))) * KDIM + (t & 3) * 8];
    const unsigned short* gB = &Wvt[((size_t)(it * 64 + (t >> 2))) * KDIM + (t & 3) * 8];
    unsigned short* lA = &As[w * 512];
    unsigned short* lB = &Bs[w * 512];

    for (int kt = 0; kt < KDIM / 32; ++kt) {
        gload16(gA + kt * 32, lA);
        gload16(gB + kt * 32, lB);
        __syncthreads();
        bf16x8 af[2], bfr[2];
        #pragma unroll
        for (int fi = 0; fi < 2; ++fi)
            af[fi] = *(bf16x8*)&As[(wr + fi * 16 + lr) * 32 + lk * 8];
        #pragma unroll
        for (int fj = 0; fj < 2; ++fj)
            bfr[fj] = *(bf16x8*)&Bs[(wc + fj * 16 + lr) * 32 + lk * 8];
        #pragma unroll
        for (int fi = 0; fi < 2; ++fi)
            #pragma unroll
            for (int fj = 0; fj < 2; ++fj)
                acc[fi][fj] = __builtin_amdgcn_mfma_f32_16x16x32_bf16(
                    af[fi], bfr[fj], acc[fi][fj], 0, 0, 0);
        __syncthreads();
    }
    #pragma unroll
    for (int fi = 0; fi < 2; ++fi)
        #pragma unroll
        for (int fj = 0; fj < 2; ++fj)
            #pragma unroll
            for (int r = 0; r < 4; ++r) {
                const int o = ot * 64 + wr + fi * 16 + lk * 4 + r;
                const int i = it * 64 + wc + fj * 16 + lr;
                Wc[(size_t)o * KDIM + i] = f2bf(acc[fi][fj][r]);
            }
}

// ---------------------------------------------------------------------------
// main_fused: out = leaky(bf16(xs) @ Wc^T + bcomb), fp32 A converted in-kernel.
// BM=BN=256, BK=64, 8 waves (2Mx4N), per-wave 128x64 = acc[8][4].
// LDS 131072 = 2 bufs x (A 32KB + B 32KB), swz128 both tiles.
// A-loads 2 tiles ahead (avA/avB reg double-buffer), B gload_lds 1 tile ahead,
// one counted vmcnt(12) per tile. Grid 256 = 1 block/CU, XCD swizzle.
// ---------------------------------------------------------------------------
__global__ __launch_bounds__(512, 2) void main_fused(
    const float* __restrict__ xs, const unsigned short* __restrict__ Wc,
    const float* __restrict__ bcomb, float* __restrict__ out) {
    extern __shared__ char lds[];  // 131072
    const int tid = threadIdx.x;
    const int w = tid >> 6, l = tid & 63;
    const int wm = w >> 2, wn = w & 3;
    const int lr = l & 15, lk = l >> 4;

    // XCD swizzle: blocks sharing mt (nt=0..3) land on one XCD for xs L2 reuse
    const int swzb = ((blockIdx.x & 7) << 5) + (blockIdx.x >> 3);
    const int mt = swzb >> 2, nt = swzb & 3;

    // reader LDS byte offsets (kh=0); kh=1 is ^64 (swz128 commutes with ^64)
    int aoff[8], boff[4];
    #pragma unroll
    for (int fi = 0; fi < 8; ++fi)
        aoff[fi] = swz128((wm * 128 + fi * 16 + lr) * 128 + lk * 16);
    #pragma unroll
    for (int fj = 0; fj < 4; ++fj)
        boff[fj] = 32768 + swz128((wn * 64 + fj * 16 + lr) * 128 + lk * 16);

    // A staging: thread handles 4 chunks (row = j*64 + tid>>3, kslot = tid&7)
    const float* gA[4];
    int awr[4];
    #pragma unroll
    for (int j = 0; j < 4; ++j) {
        const int row = j * 64 + (tid >> 3);
        gA[j] = xs + ((size_t)(mt * 256 + row)) * KDIM + (tid & 7) * 8;
        awr[j] = swz128(row * 128 + (tid & 7) * 16);
    }
    // B staging: 4 chunks, pre-swizzled global source, linear gload_lds dest
    const char* gB[4];
    #pragma unroll
    for (int j = 0; j < 4; ++j) {
        const int q = j * 8192 + w * 1024 + l * 16;
        const int p = swz128(q);
        gB[j] = (const char*)Wc + ((size_t)(nt * 256 + (p >> 7))) * 2048 + (p & 127);
    }
    const int bofs[4] = { 32768 + w * 1024, 32768 + 8192 + w * 1024,
                          32768 + 16384 + w * 1024, 32768 + 24576 + w * 1024 };

    f32x4 acc[8][4] = {};
    float4 avA[8], avB[8];

#define STAGE_A(AV, TT)                                                        \
    _Pragma("unroll")                                                          \
    for (int j = 0; j < 4; ++j) {                                              \
        AV[2 * j]     = *(const float4*)(gA[j] + (TT) * 64);                   \
        AV[2 * j + 1] = *(const float4*)(gA[j] + (TT) * 64 + 4);               \
    }

    // ---- prologue: A0->avA, B0->buf0, A1->avB, cvt A0 -> buf0 ----
    STAGE_A(avA, 0);
    #pragma unroll
    for (int j = 0; j < 4; ++j)
        gload16(gB[j], lds + bofs[j]);
    STAGE_A(avB, 1);
    *(u16x8*)(lds + awr[0]) = pack8(avA[0], avA[1]);   // auto-waits avA regs
    *(u16x8*)(lds + awr[1]) = pack8(avA[2], avA[3]);
    *(u16x8*)(lds + awr[2]) = pack8(avA[4], avA[5]);
    *(u16x8*)(lds + awr[3]) = pack8(avA[6], avA[7]);
    asm volatile("s_waitcnt vmcnt(8)" ::: "memory");   // B0 done (A1 younger)
    asm volatile("s_waitcnt lgkmcnt(0)" ::: "memory");
    __builtin_amdgcn_s_barrier();

#define MFMA16(ACCI, AF, BF)                                                   \
    _Pragma("unroll")                                                          \
    for (int fi = 0; fi < 4; ++fi)                                             \
        _Pragma("unroll")                                                      \
        for (int fj = 0; fj < 4; ++fj)                                         \
            acc[(ACCI) + fi][fj] = __builtin_amdgcn_mfma_f32_16x16x32_bf16(    \
                (AF)[fi], (BF)[fj], acc[(ACCI) + fi][fj], 0, 0, 0)

#define PH_SYNC()                                                              \
    __builtin_amdgcn_s_barrier();                                              \
    asm volatile("s_waitcnt lgkmcnt(0)" ::: "memory");                         \
    __builtin_amdgcn_sched_barrier(0)

    // ITER T: compute tile T from buf[T&1]; AEN: issue A(T+2)->AVL;
    // BEN: issue B(T+1)->nbuf; CEN: cvt AVC (=A(T+1)) -> nbuf; WN: top vmcnt.
#define ITER(T, AVL, AVC, AEN, BEN, CEN, WN)                                   \
    do {                                                                       \
        const char* cbuf = lds + (((T) & 1) << 16);                            \
        char* nbuf = lds + ((((T) & 1) ^ 1) << 16);                            \
        if (AEN) { STAGE_A(AVL, (T) + 2); }                                    \
        if (BEN) {                                                             \
            gload16(gB[0] + ((size_t)(T) + 1) * 128, nbuf + bofs[0]);          \
            gload16(gB[1] + ((size_t)(T) + 1) * 128, nbuf + bofs[1]);          \
            gload16(gB[2] + ((size_t)(T) + 1) * 128, nbuf + bofs[2]);          \
            gload16(gB[3] + ((size_t)(T) + 1) * 128, nbuf + bofs[3]);          \
        }                                                                      \
        asm volatile("s_waitcnt vmcnt(" #WN ")" ::: "memory");                 \
        __builtin_amdgcn_s_barrier();                                          \
        /* P0: B kh0 + A kh0 rows 0-3 */                                       \
        bf16x8 b0[4], a0[4];                                                   \
        _Pragma("unroll")                                                      \
        for (int fj = 0; fj < 4; ++fj)                                         \
            b0[fj] = *(const bf16x8*)(cbuf + boff[fj]);                        \
        _Pragma("unroll")                                                      \
        for (int fi = 0; fi < 4; ++fi)                                         \
            a0[fi] = *(const bf16x8*)(cbuf + aoff[fi]);                        \
        PH_SYNC();                                                             \
        __builtin_amdgcn_s_setprio(1);                                         \
        MFMA16(0, a0, b0);                                                     \
        __builtin_amdgcn_s_setprio(0);                                         \
        __builtin_amdgcn_s_barrier();                                          \
        /* P1: A kh0 rows 4-7; then cvt+write A(T+1) j01 */                    \
        bf16x8 a1[4];                                                          \
        _Pragma("unroll")                                                      \
        for (int fi = 0; fi < 4; ++fi)                                         \
            a1[fi] = *(const bf16x8*)(cbuf + aoff[4 + fi]);                    \
        PH_SYNC();                                                             \
        __builtin_amdgcn_s_setprio(1);                                         \
        MFMA16(4, a1, b0);                                                     \
        __builtin_amdgcn_s_setprio(0);                                         \
        if (CEN) {                                                             \
            *(u16x8*)(nbuf + awr[0]) = pack8(AVC[0], AVC[1]);                  \
            *(u16x8*)(nbuf + awr[1]) = pack8(AVC[2], AVC[3]);                  \
        }                                                                      \
        __builtin_amdgcn_s_barrier();                                          \
        /* P2: B kh1 + A kh1 rows 0-3; then cvt+write A(T+1) j23 */            \
        bf16x8 b1[4], a2[4];                                                   \
        _Pragma("unroll")                                                      \
        for (int fj = 0; fj < 4; ++fj)                                         \
            b1[fj] = *(const bf16x8*)(cbuf + (boff[fj] ^ 64));                 \
        _Pragma("unroll")                                                      \
        for (int fi = 0; fi < 4; ++fi)                                         \
            a2[fi] = *(const bf16x8*)(cbuf + (aoff[fi] ^ 64));                 \
        PH_SYNC();                                                             \
        __builtin_amdgcn_s_setprio(1);                                         \
        MFMA16(0, a2, b1);                                                     \
        __builtin_amdgcn_s_setprio(0);                                         \
        if (CEN) {                                                             \
            *(u16x8*)(nbuf + awr[2]) = pack8(AVC[4], AVC[5]);                  \
            *(u16x8*)(nbuf + awr[3]) = pack8(AVC[6], AVC[7]);                  \
        }                                                                      \
        __builtin_amdgcn_s_barrier();                                          \
        /* P3: A kh1 rows 4-7 (no trailing barrier; next top barrier covers) */\
        bf16x8 a3[4];                                                          \
        _Pragma("unroll")                                                      \
        for (int fi = 0; fi < 4; ++fi)                                         \
            a3[fi] = *(const bf16x8*)(cbuf + (aoff[4 + fi] ^ 64));             \
        PH_SYNC();                                                             \
        __builtin_amdgcn_s_setprio(1);                                         \
        MFMA16(4, a3, b1);                                                     \
        __builtin_amdgcn_s_setprio(0);                                         \
    } while (0)

    // steady: T=0..13 (issue A up to 15, B up to 14), counted vmcnt(12)
    for (int t = 0; t < NKT - 2; t += 2) {
        ITER(t,     avA, avB, 1, 1, 1, 12);
        ITER(t + 1, avB, avA, 1, 1, 1, 12);
    }
    // T=14: no A issue; B15; cvt A15 (in avB); B14 done at vmcnt(4)
    ITER(14, avA, avB, 0, 1, 1, 4);
    // T=15: nothing staged; B15 done at vmcnt(0)
    ITER(15, avA, avA, 0, 0, 0, 0);
#undef ITER
#undef PH_SYNC
#undef MFMA16
#undef STAGE_A

    // epilogue: + bias, leaky_relu, fp32 store
    #pragma unroll
    for (int fi = 0; fi < 8; ++fi)
        #pragma unroll
        for (int fj = 0; fj < 4; ++fj) {
            const int col = nt * 256 + wn * 64 + fj * 16 + lr;
            const float b = bcomb[col];
            #pragma unroll
            for (int r = 0; r < 4; ++r) {
                const int row = mt * 256 + wm * 128 + fi * 16 + lk * 4 + r;
                float v = acc[fi][fj][r] + b;
                out[(size_t)row * NDIM + col] = v >= 0.f ? v : 0.01f * v;
            }
        }
}

// ---------------------------------------------------------------------------
// Fallback main GEMM (fused fp32->bf16 A path, 128x128) if ws is too small.
// ---------------------------------------------------------------------------
__global__ __launch_bounds__(256) void main_gemm_f32(
    const float* __restrict__ X, const unsigned short* __restrict__ Wc,
    const float* __restrict__ bcomb, float* __restrict__ out) {
    __shared__ unsigned short As[128 * 32];
    __shared__ unsigned short Bs[128 * 32];
    const int t = threadIdx.x;
    const int nt = blockIdx.x & 7;
    const int mt = blockIdx.x >> 3;
    const int w = t >> 6, l = t & 63;
    const int wr = (w >> 1) * 64, wcc = (w & 1) * 64;
    const int lr = l & 15, lk = l >> 4;

    f32x4 acc[4][4] = {};

    const int arow = t >> 3;
    const int akq = t & 7;
    const int brow = t >> 2;
    const int bc4 = t & 3;

    for (int kt = 0; kt < KDIM / 32; ++kt) {
        float4 av[4];
        #pragma unroll
        for (int j = 0; j < 4; ++j) {
            const int row = j * 32 + arow;
            av[j] = *(const float4*)&X[(mt * 128 + row) * KDIM + kt * 32 + akq * 4];
        }
        __syncthreads();
        #pragma unroll
        for (int j = 0; j < 4; ++j) {
            const int row = j * 32 + arow;
            u16x4 p = { f2bf(av[j].x), f2bf(av[j].y), f2bf(av[j].z), f2bf(av[j].w) };
            *(u16x4*)&As[row * 32 + akq * 4] = p;
        }
        #pragma unroll
        for (int j = 0; j < 2; ++j) {
            const int row = j * 64 + brow;
            const unsigned short* g = &Wc[(nt * 128 + row) * KDIM + kt * 32 + bc4 * 8];
            unsigned short* ldst = &Bs[(j * 256 + w * 64) * 8];
            gload16(g, ldst);
        }
        __syncthreads();
        bf16x8 af[4], bfr[4];
        #pragma unroll
        for (int fi = 0; fi < 4; ++fi)
            af[fi] = *(bf16x8*)&As[(wr + fi * 16 + lr) * 32 + lk * 8];
        #pragma unroll
        for (int fj = 0; fj < 4; ++fj)
            bfr[fj] = *(bf16x8*)&Bs[(wcc + fj * 16 + lr) * 32 + lk * 8];
        #pragma unroll
        for (int fi = 0; fi < 4; ++fi)
            #pragma unroll
            for (int fj = 0; fj < 4; ++fj)
                acc[fi][fj] = __builtin_amdgcn_mfma_f32_16x16x32_bf16(
                    af[fi], bfr[fj], acc[fi][fj], 0, 0, 0);
    }

    #pragma unroll
    for (int fi = 0; fi < 4; ++fi)
        #pragma unroll
        for (int fj = 0; fj < 4; ++fj) {
            const int col = nt * 128 + wcc + fj * 16 + lr;
            const float b = bcomb[col];
            #pragma unroll
            for (int r = 0; r < 4; ++r) {
                const int row = mt * 128 + wr + fi * 16 + lk * 4 + r;
                float v = acc[fi][fj][r] + b;
                out[row * NDIM + col] = v >= 0.f ? v : 0.01f * v;
            }
        }
}

extern "C" void kernel_launch(void* const* d_in, const int* in_sizes, int n_in,
                              void* d_out, int out_size, void* d_ws, size_t ws_size,
                              hipStream_t stream) {
    const float* xs   = (const float*)d_in[0];
    // d_in[1] mask unused: softmax row-sums are exactly 1.
    const float* Wv   = (const float*)d_in[6];
    const float* bv   = (const float*)d_in[7];
    const float* Wlin = (const float*)d_in[8];
    const float* blin = (const float*)d_in[9];

    unsigned short* Wc = (unsigned short*)d_ws;                         // 2 MB
    float* bcomb = (float*)((char*)d_ws + 2097152);                     // 4 KB
    float* out = (float*)d_out;

    // transient scratch in d_out (64 MB, fully overwritten by the final GEMM)
    unsigned short* Wvt = (unsigned short*)d_out;                       // 2 MB
    unsigned short* Wlb = (unsigned short*)((char*)d_out + 2097152);    // 2 MB

    const size_t NEED = 2101248;
    hipLaunchKernelGGL(prep0_kernel, dim3(768), dim3(256), 0, stream,
                       Wv, Wlin, bv, blin, Wvt, Wlb, bcomb);
    hipLaunchKernelGGL(wcomb_kernel, dim3(256), dim3(256), 0, stream,
                       Wlb, Wvt, Wc);
    if (ws_size >= NEED) {
        (void)hipFuncSetAttribute((const void*)main_fused,
                                  hipFuncAttributeMaxDynamicSharedMemorySize,
                                  131072);
        hipLaunchKernelGGL(main_fused, dim3(256), dim3(512), 131072, stream,
                           xs, Wc, bcomb, out);
    } else {
        hipLaunchKernelGGL(main_gemm_f32, dim3((M_TOT / 128) * (NDIM / 128)),
                           dim3(256), 0, stream, xs, Wc, bcomb, out);
    }
}

// Round 7
// 79.134 us; speedup vs baseline: 1.7159x; 1.7159x over previous
//
#include <hip/hip_runtime.h>
#include <hip/hip_bf16.h>
#include <stdint.h>

// Problem: B=16, S=1024, IN=1024, OUT=1024.
// Reference collapses: softmax row-sums are exactly 1 (key mask always has >=1
// live column), so out = leaky_relu(xs @ (Wlin@Wv)^T + (Wlin@bv + blin)).
//
// Round 7: round-6's counted-vmcnt schedule caused VGPR spills (avA+avB = 64
// extra VGPRs over the 2-wave/SIMD budget; WRITE_SIZE 204MB = scratch).
// Single A reg buffer: A(T+1) issued at top of iter T, cvt in P2/P3; B(T+1)
// gload_lds one tile ahead; one counted vmcnt(12) per tile (T4, never 0).

#define M_TOT 16384   // B*S
#define KDIM  1024
#define NDIM  1024
#define NKT   16      // K-tiles of BK=64 in main GEMM

typedef __attribute__((ext_vector_type(8))) short bf16x8;
typedef __attribute__((ext_vector_type(4))) float f32x4;
typedef __attribute__((ext_vector_type(4))) unsigned short u16x4;
typedef __attribute__((ext_vector_type(8))) unsigned short u16x8;

static __device__ __forceinline__ unsigned short f2bf(float f) {
    union { float f; unsigned int u; } v; v.f = f;
    unsigned int u = v.u;
    return (unsigned short)((u + 0x7fffu + ((u >> 16) & 1u)) >> 16);  // RNE
}

static __device__ __forceinline__ u16x8 pack8(float4 a, float4 b) {
    u16x8 p = { f2bf(a.x), f2bf(a.y), f2bf(a.z), f2bf(a.w),
                f2bf(b.x), f2bf(b.y), f2bf(b.z), f2bf(b.w) };
    return p;
}

static __device__ __forceinline__ void gload16(const void* g, void* l) {
    __builtin_amdgcn_global_load_lds(
        (__attribute__((address_space(1))) void*)(g),
        (__attribute__((address_space(3))) void*)(l), 16, 0, 0);
}

// Involutive byte-swizzle for [rows][64]bf16 (128B-stride) LDS tiles: XOR row
// bits (7-9) into 16B-slot bits (4-6). 16-way column conflict -> free 2-way.
static __device__ __forceinline__ int swz128(int p) {
    return p ^ (((p >> 7) & 7) << 4);
}

// ---------------------------------------------------------------------------
// prep0: [0,256) transpose Wv[d][i] -> Wvt[i][d] bf16 (64x64 tiles, padded
//        fp32 LDS); [256,512) Wlin -> Wlb bf16; [512,768) bias fold.
// ---------------------------------------------------------------------------
__global__ __launch_bounds__(256) void prep0_kernel(
    const float* __restrict__ Wv, const float* __restrict__ Wlin,
    const float* __restrict__ bv, const float* __restrict__ blin,
    unsigned short* __restrict__ Wvt, unsigned short* __restrict__ Wlb,
    float* __restrict__ bcomb) {
    __shared__ float Tl[64 * 65];
    const int bid = blockIdx.x;
    const int t = threadIdx.x;

    if (bid < 256) {
        const int dt = bid >> 4;
        const int it = bid & 15;
        const int r = t >> 2;
        const int c0 = (t & 3) * 16;
        #pragma unroll
        for (int u = 0; u < 4; ++u) {
            float4 v = *(const float4*)&Wv[((size_t)(dt * 64 + r)) * NDIM + it * 64 + c0 + 4 * u];
            Tl[r * 65 + c0 + 4 * u + 0] = v.x;
            Tl[r * 65 + c0 + 4 * u + 1] = v.y;
            Tl[r * 65 + c0 + 4 * u + 2] = v.z;
            Tl[r * 65 + c0 + 4 * u + 3] = v.w;
        }
        __syncthreads();
        const int i = t >> 2;
        const int dq = (t & 3) * 16;
        float v[16];
        #pragma unroll
        for (int u = 0; u < 16; ++u) v[u] = Tl[(dq + u) * 65 + i];
        u16x8 p0 = { f2bf(v[0]), f2bf(v[1]), f2bf(v[2]), f2bf(v[3]),
                     f2bf(v[4]), f2bf(v[5]), f2bf(v[6]), f2bf(v[7]) };
        u16x8 p1 = { f2bf(v[8]), f2bf(v[9]), f2bf(v[10]), f2bf(v[11]),
                     f2bf(v[12]), f2bf(v[13]), f2bf(v[14]), f2bf(v[15]) };
        unsigned short* dst = &Wvt[((size_t)(it * 64 + i)) * KDIM + dt * 64 + dq];
        *(u16x8*)dst = p0;
        *(u16x8*)(dst + 8) = p1;
    } else if (bid < 512) {
        const size_t idx = (((size_t)(bid - 256)) * 256 + t) * 16;
        float4 a = *(const float4*)&Wlin[idx];
        float4 b = *(const float4*)&Wlin[idx + 4];
        float4 c = *(const float4*)&Wlin[idx + 8];
        float4 d = *(const float4*)&Wlin[idx + 12];
        *(u16x8*)&Wlb[idx] = pack8(a, b);
        *(u16x8*)&Wlb[idx + 8] = pack8(c, d);
    } else {
        const int wave = t >> 6, lane = t & 63;
        const int o = (bid - 512) * 4 + wave;
        float s = 0.f;
        for (int d = lane; d < KDIM; d += 64) s += Wlin[o * KDIM + d] * bv[d];
        #pragma unroll
        for (int off = 32; off > 0; off >>= 1) s += __shfl_down(s, off, 64);
        if (lane == 0) bcomb[o] = s + blin[o];
    }
}

// ---------------------------------------------------------------------------
// wcomb: Wc[o][i] = sum_d Wlb[o][d] * Wvt[i][d]. 64x64 tiles, 256 blocks,
// 4 waves (2x2 of 32x32), both operands via global_load_lds.
// ---------------------------------------------------------------------------
__global__ __launch_bounds__(256) void wcomb_kernel(
    const unsigned short* __restrict__ Wlb, const unsigned short* __restrict__ Wvt,
    unsigned short* __restrict__ Wc) {
    __shared__ unsigned short As[64 * 32];
    __shared__ unsigned short Bs[64 * 32];
    const int t = threadIdx.x;
    const int ot = blockIdx.x >> 4;
    const int it = blockIdx.x & 15;
    const int w = t >> 6, l = t & 63;
    const int wr = (w >> 1) * 32, wc = (w & 1) * 32;
    const int lr = l & 15, lk = l >> 4;

    f32x4 acc[2][2] = {};

    const unsigned short* gA = &Wlb[((size_t)(ot * 64 + (t >> 2))) * KDIM + (t & 3) * 8];
    const unsigned short* gB = &Wvt[((size_t)(it * 64 + (t >> 2))) * KDIM + (t & 3) * 8];
    unsigned short* lA = &As[w * 512];
    unsigned short* lB = &Bs[w * 512];

    for (int kt = 0; kt < KDIM / 32; ++kt) {
        gload16(gA + kt * 32, lA);
        gload16(gB + kt * 32, lB);
        __syncthreads();
        bf16x8 af[2], bfr[2];
        #pragma unroll
        for (int fi = 0; fi < 2; ++fi)
            af[fi] = *(bf16x8*)&As[(wr + fi * 16 + lr) * 32 + lk * 8];
        #pragma unroll
        for (int fj = 0; fj < 2; ++fj)
            bfr[fj] = *(bf16x8*)&Bs[(wc + fj * 16 + lr) * 32 + lk * 8];
        #pragma unroll
        for (int fi = 0; fi < 2; ++fi)
            #pragma unroll
            for (int fj = 0; fj < 2; ++fj)
                acc[fi][fj] = __builtin_amdgcn_mfma_f32_16x16x32_bf16(
                    af[fi], bfr[fj], acc[fi][fj], 0, 0, 0);
        __syncthreads();
    }
    #pragma unroll
    for (int fi = 0; fi < 2; ++fi)
        #pragma unroll
        for (int fj = 0; fj < 2; ++fj)
            #pragma unroll
            for (int r = 0; r < 4; ++r) {
                const int o = ot * 64 + wr + fi * 16 + lk * 4 + r;
                const int i = it * 64 + wc + fj * 16 + lr;
                Wc[(size_t)o * KDIM + i] = f2bf(acc[fi][fj][r]);
            }
}

// ---------------------------------------------------------------------------
// main_fused: out = leaky(bf16(xs) @ Wc^T + bcomb), fp32 A converted in-kernel.
// BM=BN=256, BK=64, 8 waves (2Mx4N), per-wave 128x64 = acc[8][4].
// LDS 131072 = 2 bufs x (A 32KB + B 32KB), swz128 both tiles.
// Single A reg buffer (avA): A(T+1) loads at top of iter T, cvt in P2/P3.
// B(T+1) gload_lds at top of iter T. One counted vmcnt(12) per tile.
// Grid 256 = 1 block/CU, XCD swizzle.
// ---------------------------------------------------------------------------
__global__ __launch_bounds__(512, 2) void main_fused(
    const float* __restrict__ xs, const unsigned short* __restrict__ Wc,
    const float* __restrict__ bcomb, float* __restrict__ out) {
    extern __shared__ char lds[];  // 131072
    const int tid = threadIdx.x;
    const int w = tid >> 6, l = tid & 63;
    const int wm = w >> 2, wn = w & 3;
    const int lr = l & 15, lk = l >> 4;

    // XCD swizzle: blocks sharing mt (nt=0..3) land on one XCD for xs L2 reuse
    const int swzb = ((blockIdx.x & 7) << 5) + (blockIdx.x >> 3);
    const int mt = swzb >> 2, nt = swzb & 3;

    // reader LDS byte offsets (kh=0); kh=1 is ^64 (swz128 commutes with ^64)
    int aoff[8], boff[4];
    #pragma unroll
    for (int fi = 0; fi < 8; ++fi)
        aoff[fi] = swz128((wm * 128 + fi * 16 + lr) * 128 + lk * 16);
    #pragma unroll
    for (int fj = 0; fj < 4; ++fj)
        boff[fj] = 32768 + swz128((wn * 64 + fj * 16 + lr) * 128 + lk * 16);

    // A staging: thread handles 4 chunks (row = j*64 + tid>>3, kslot = tid&7)
    const float* gA[4];
    int awr[4];
    #pragma unroll
    for (int j = 0; j < 4; ++j) {
        const int row = j * 64 + (tid >> 3);
        gA[j] = xs + ((size_t)(mt * 256 + row)) * KDIM + (tid & 7) * 8;
        awr[j] = swz128(row * 128 + (tid & 7) * 16);
    }
    // B staging: 4 chunks, pre-swizzled global source, linear gload_lds dest
    const char* gB[4];
    #pragma unroll
    for (int j = 0; j < 4; ++j) {
        const int q = j * 8192 + w * 1024 + l * 16;
        const int p = swz128(q);
        gB[j] = (const char*)Wc + ((size_t)(nt * 256 + (p >> 7))) * 2048 + (p & 127);
    }
    const int bofs[4] = { 32768 + w * 1024, 32768 + 8192 + w * 1024,
                          32768 + 16384 + w * 1024, 32768 + 24576 + w * 1024 };

    f32x4 acc[8][4] = {};
    float4 avA[8];

#define STAGE_A(TT)                                                            \
    _Pragma("unroll")                                                          \
    for (int j = 0; j < 4; ++j) {                                              \
        avA[2 * j]     = *(const float4*)(gA[j] + (TT) * 64);                  \
        avA[2 * j + 1] = *(const float4*)(gA[j] + (TT) * 64 + 4);              \
    }

    // ---- prologue: A0->avA, B0->buf0, cvt A0 -> buf0 ----
    STAGE_A(0);
    #pragma unroll
    for (int j = 0; j < 4; ++j)
        gload16(gB[j], lds + bofs[j]);
    *(u16x8*)(lds + awr[0]) = pack8(avA[0], avA[1]);   // compiler waits avA
    *(u16x8*)(lds + awr[1]) = pack8(avA[2], avA[3]);
    *(u16x8*)(lds + awr[2]) = pack8(avA[4], avA[5]);
    *(u16x8*)(lds + awr[3]) = pack8(avA[6], avA[7]);
    asm volatile("s_waitcnt vmcnt(0)" ::: "memory");   // B0 resident
    asm volatile("s_waitcnt lgkmcnt(0)" ::: "memory");
    __builtin_amdgcn_s_barrier();

#define MFMA16(ACCI, AF, BF)                                                   \
    _Pragma("unroll")                                                          \
    for (int fi = 0; fi < 4; ++fi)                                             \
        _Pragma("unroll")                                                      \
        for (int fj = 0; fj < 4; ++fj)                                         \
            acc[(ACCI) + fi][fj] = __builtin_amdgcn_mfma_f32_16x16x32_bf16(    \
                (AF)[fi], (BF)[fj], acc[(ACCI) + fi][fj], 0, 0, 0)

#define PH_SYNC()                                                              \
    __builtin_amdgcn_s_barrier();                                              \
    asm volatile("s_waitcnt lgkmcnt(0)" ::: "memory");                         \
    __builtin_amdgcn_sched_barrier(0)

    // ITER T: compute tile T from buf[T&1]. SEN: issue A(T+1)->avA and
    // B(T+1)->nbuf at top, cvt avA->nbuf in P2/P3. WN: counted top vmcnt.
#define ITER(T, SEN, WN)                                                       \
    do {                                                                       \
        const char* cbuf = lds + (((T) & 1) << 16);                            \
        char* nbuf = lds + ((((T) & 1) ^ 1) << 16);                            \
        if (SEN) {                                                             \
            STAGE_A((T) + 1);                                                  \
            gload16(gB[0] + ((size_t)(T) + 1) * 128, nbuf + bofs[0]);          \
            gload16(gB[1] + ((size_t)(T) + 1) * 128, nbuf + bofs[1]);          \
            gload16(gB[2] + ((size_t)(T) + 1) * 128, nbuf + bofs[2]);          \
            gload16(gB[3] + ((size_t)(T) + 1) * 128, nbuf + bofs[3]);          \
        }                                                                      \
        asm volatile("s_waitcnt vmcnt(" #WN ")" ::: "memory");                 \
        __builtin_amdgcn_s_barrier();                                          \
        /* P0: B kh0 + A kh0 rows 0-3 */                                       \
        bf16x8 b0[4], a0[4];                                                   \
        _Pragma("unroll")                                                      \
        for (int fj = 0; fj < 4; ++fj)                                         \
            b0[fj] = *(const bf16x8*)(cbuf + boff[fj]);                        \
        _Pragma("unroll")                                                      \
        for (int fi = 0; fi < 4; ++fi)                                         \
            a0[fi] = *(const bf16x8*)(cbuf + aoff[fi]);                        \
        PH_SYNC();                                                             \
        __builtin_amdgcn_s_setprio(1);                                         \
        MFMA16(0, a0, b0);                                                     \
        __builtin_amdgcn_s_setprio(0);                                         \
        __builtin_amdgcn_s_barrier();                                          \
        /* P1: A kh0 rows 4-7 */                                               \
        bf16x8 a1[4];                                                          \
        _Pragma("unroll")                                                      \
        for (int fi = 0; fi < 4; ++fi)                                         \
            a1[fi] = *(const bf16x8*)(cbuf + aoff[4 + fi]);                    \
        PH_SYNC();                                                             \
        __builtin_amdgcn_s_setprio(1);                                         \
        MFMA16(4, a1, b0);                                                     \
        __builtin_amdgcn_s_setprio(0);                                         \
        __builtin_amdgcn_s_barrier();                                          \
        /* P2: B kh1 + A kh1 rows 0-3; then cvt+write A(T+1) j01 */            \
        bf16x8 b1[4], a2[4];                                                   \
        _Pragma("unroll")                                                      \
        for (int fj = 0; fj < 4; ++fj)                                         \
            b1[fj] = *(const bf16x8*)(cbuf + (boff[fj] ^ 64));                 \
        _Pragma("unroll")                                                      \
        for (int fi = 0; fi < 4; ++fi)                                         \
            a2[fi] = *(const bf16x8*)(cbuf + (aoff[fi] ^ 64));                 \
        PH_SYNC();                                                             \
        __builtin_amdgcn_s_setprio(1);                                         \
        MFMA16(0, a2, b1);                                                     \
        __builtin_amdgcn_s_setprio(0);                                         \
        if (SEN) {                                                             \
            *(u16x8*)(nbuf + awr[0]) = pack8(avA[0], avA[1]);                  \
            *(u16x8*)(nbuf + awr[1]) = pack8(avA[2], avA[3]);                  \
        }                                                                      \
        __builtin_amdgcn_s_barrier();                                          \
        /* P3: A kh1 rows 4-7; then cvt+write A(T+1) j23 */                    \
        bf16x8 a3[4];                                                          \
        _Pragma("unroll")                                                      \
        for (int fi = 0; fi < 4; ++fi)                                         \
            a3[fi] = *(const bf16x8*)(cbuf + (aoff[4 + fi] ^ 64));             \
        PH_SYNC();                                                             \
        __builtin_amdgcn_s_setprio(1);                                         \
        MFMA16(4, a3, b1);                                                     \
        __builtin_amdgcn_s_setprio(0);                                         \
        if (SEN) {                                                             \
            *(u16x8*)(nbuf + awr[2]) = pack8(avA[4], avA[5]);                  \
            *(u16x8*)(nbuf + awr[3]) = pack8(avA[6], avA[7]);                  \
        }                                                                      \
    } while (0)

    // steady state: T=0..14 stage tile T+1; counted vmcnt(12) =
    // (A(T+1) 8 loads + B(T+1) 4 loads younger than B(T))
    for (int t = 0; t < NKT - 1; ++t) {
        ITER(t, 1, 12);
    }
    // T=15: nothing staged; B(15) is the only outstanding VMEM
    ITER(15, 0, 0);
#undef ITER
#undef PH_SYNC
#undef MFMA16
#undef STAGE_A

    // epilogue: + bias, leaky_relu, fp32 store
    #pragma unroll
    for (int fi = 0; fi < 8; ++fi)
        #pragma unroll
        for (int fj = 0; fj < 4; ++fj) {
            const int col = nt * 256 + wn * 64 + fj * 16 + lr;
            const float b = bcomb[col];
            #pragma unroll
            for (int r = 0; r < 4; ++r) {
                const int row = mt * 256 + wm * 128 + fi * 16 + lk * 4 + r;
                float v = acc[fi][fj][r] + b;
                out[(size_t)row * NDIM + col] = v >= 0.f ? v : 0.01f * v;
            }
        }
}

// ---------------------------------------------------------------------------
// Fallback main GEMM (fused fp32->bf16 A path, 128x128) if ws is too small.
// ---------------------------------------------------------------------------
__global__ __launch_bounds__(256) void main_gemm_f32(
    const float* __restrict__ X, const unsigned short* __restrict__ Wc,
    const float* __restrict__ bcomb, float* __restrict__ out) {
    __shared__ unsigned short As[128 * 32];
    __shared__ unsigned short Bs[128 * 32];
    const int t = threadIdx.x;
    const int nt = blockIdx.x & 7;
    const int mt = blockIdx.x >> 3;
    const int w = t >> 6, l = t & 63;
    const int wr = (w >> 1) * 64, wcc = (w & 1) * 64;
    const int lr = l & 15, lk = l >> 4;

    f32x4 acc[4][4] = {};

    const int arow = t >> 3;
    const int akq = t & 7;
    const int brow = t >> 2;
    const int bc4 = t & 3;

    for (int kt = 0; kt < KDIM / 32; ++kt) {
        float4 av[4];
        #pragma unroll
        for (int j = 0; j < 4; ++j) {
            const int row = j * 32 + arow;
            av[j] = *(const float4*)&X[(mt * 128 + row) * KDIM + kt * 32 + akq * 4];
        }
        __syncthreads();
        #pragma unroll
        for (int j = 0; j < 4; ++j) {
            const int row = j * 32 + arow;
            u16x4 p = { f2bf(av[j].x), f2bf(av[j].y), f2bf(av[j].z), f2bf(av[j].w) };
            *(u16x4*)&As[row * 32 + akq * 4] = p;
        }
        #pragma unroll
        for (int j = 0; j < 2; ++j) {
            const int row = j * 64 + brow;
            const unsigned short* g = &Wc[(nt * 128 + row) * KDIM + kt * 32 + bc4 * 8];
            unsigned short* ldst = &Bs[(j * 256 + w * 64) * 8];
            gload16(g, ldst);
        }
        __syncthreads();
        bf16x8 af[4], bfr[4];
        #pragma unroll
        for (int fi = 0; fi < 4; ++fi)
            af[fi] = *(bf16x8*)&As[(wr + fi * 16 + lr) * 32 + lk * 8];
        #pragma unroll
        for (int fj = 0; fj < 4; ++fj)
            bfr[fj] = *(bf16x8*)&Bs[(wcc + fj * 16 + lr) * 32 + lk * 8];
        #pragma unroll
        for (int fi = 0; fi < 4; ++fi)
            #pragma unroll
            for (int fj = 0; fj < 4; ++fj)
                acc[fi][fj] = __builtin_amdgcn_mfma_f32_16x16x32_bf16(
                    af[fi], bfr[fj], acc[fi][fj], 0, 0, 0);
    }

    #pragma unroll
    for (int fi = 0; fi < 4; ++fi)
        #pragma unroll
        for (int fj = 0; fj < 4; ++fj) {
            const int col = nt * 128 + wcc + fj * 16 + lr;
            const float b = bcomb[col];
            #pragma unroll
            for (int r = 0; r < 4; ++r) {
                const int row = mt * 128 + wr + fi * 16 + lk * 4 + r;
                float v = acc[fi][fj][r] + b;
                out[row * NDIM + col] = v >= 0.f ? v : 0.01f * v;
            }
        }
}

extern "C" void kernel_launch(void* const* d_in, const int* in_sizes, int n_in,
                              void* d_out, int out_size, void* d_ws, size_t ws_size,
                              hipStream_t stream) {
    const float* xs   = (const float*)d_in[0];
    // d_in[1] mask unused: softmax row-sums are exactly 1.
    const float* Wv   = (const float*)d_in[6];
    const float* bv   = (const float*)d_in[7];
    const float* Wlin = (const float*)d_in[8];
    const float* blin = (const float*)d_in[9];

    unsigned short* Wc = (unsigned short*)d_ws;                         // 2 MB
    float* bcomb = (float*)((char*)d_ws + 2097152);                     // 4 KB
    float* out = (float*)d_out;

    // transient scratch in d_out (64 MB, fully overwritten by the final GEMM)
    unsigned short* Wvt = (unsigned short*)d_out;                       // 2 MB
    unsigned short* Wlb = (unsigned short*)((char*)d_out + 2097152);    // 2 MB

    const size_t NEED = 2101248;
    hipLaunchKernelGGL(prep0_kernel, dim3(768), dim3(256), 0, stream,
                       Wv, Wlin, bv, blin, Wvt, Wlb, bcomb);
    hipLaunchKernelGGL(wcomb_kernel, dim3(256), dim3(256), 0, stream,
                       Wlb, Wvt, Wc);
    if (ws_size >= NEED) {
        (void)hipFuncSetAttribute((const void*)main_fused,
                                  hipFuncAttributeMaxDynamicSharedMemorySize,
                                  131072);
        hipLaunchKernelGGL(main_fused, dim3(256), dim3(512), 131072, stream,
                           xs, Wc, bcomb, out);
    } else {
        hipLaunchKernelGGL(main_gemm_f32, dim3((M_TOT / 128) * (NDIM / 128)),
                           dim3(256), 0, stream, xs, Wc, bcomb, out);
    }
}